// Round 3
// baseline (497.607 us; speedup 1.0000x reference)
//
#include <hip/hip_runtime.h>
#include <math.h>

#define B_ 64
#define D_ 1024
#define H_ 1024
#define KSPLIT 4
#define KPB (D_/KSPLIT)   // 256 K-depth per block in K2
#define KC 64             // K chunk staged in LDS

// ---- workspace layout (floats) ----
#define OFF_XN    0
#define OFF_PART  (OFF_XN + B_*D_)                 // 6 matrices x KSPLIT partials
#define OFF_FT    (OFF_PART + KSPLIT*6*B_*H_)
#define OFF_IP    (OFF_FT + B_*H_)
#define OFF_OT    (OFF_IP + B_*H_)
#define OFF_QT    (OFF_OT + B_*H_)
#define OFF_KT    (OFF_QT + B_*H_)
#define OFF_VT    (OFF_KT + B_*H_)
#define OFF_DIV   (OFF_VT + B_*H_)

// ---- output layout (floats) ----
#define OUT_H 0
#define OUT_C (B_*H_)
#define OUT_N (OUT_C + B_*H_*H_)
#define OUT_M (OUT_N + B_*H_)

__device__ __forceinline__ float clip100(float v) {
    return fminf(fmaxf(v, -100.0f), 100.0f);
}

// ---------------- K1: LayerNorm ----------------
__global__ __launch_bounds__(256) void k1_ln(const float* __restrict__ x,
                                             const float* __restrict__ gamma,
                                             const float* __restrict__ beta,
                                             float* __restrict__ xn) {
    int b = blockIdx.x;
    int t = threadIdx.x;
    const float4* x4 = (const float4*)(x + b * D_);
    float4 v = x4[t];
    __shared__ float red[4];

    float s = v.x + v.y + v.z + v.w;
    #pragma unroll
    for (int off = 32; off; off >>= 1) s += __shfl_xor(s, off);
    if ((t & 63) == 0) red[t >> 6] = s;
    __syncthreads();
    float mean = (red[0] + red[1] + red[2] + red[3]) * (1.0f / D_);

    float dx = v.x - mean, dy = v.y - mean, dz = v.z - mean, dw = v.w - mean;
    float s2 = dx*dx + dy*dy + dz*dz + dw*dw;
    __syncthreads();
    #pragma unroll
    for (int off = 32; off; off >>= 1) s2 += __shfl_xor(s2, off);
    if ((t & 63) == 0) red[t >> 6] = s2;
    __syncthreads();
    float var = (red[0] + red[1] + red[2] + red[3]) * (1.0f / D_);
    float rstd = 1.0f / sqrtf(var + 1e-5f);

    float4 g = ((const float4*)gamma)[t];
    float4 be = ((const float4*)beta)[t];
    float4 o;
    o.x = dx * rstd * g.x + be.x;
    o.y = dy * rstd * g.y + be.y;
    o.z = dz * rstd * g.z + be.z;
    o.w = dw * rstd * g.w + be.w;
    ((float4*)(xn + b * D_))[t] = o;
}

// ---------------- K2: 6x GEMM (xn @ W), K-split partials ----------------
__global__ __launch_bounds__(256) void k2_gemm(const float* __restrict__ xn,
                                               const float* __restrict__ W0,
                                               const float* __restrict__ W1,
                                               const float* __restrict__ W2,
                                               const float* __restrict__ W3,
                                               const float* __restrict__ W4,
                                               const float* __restrict__ W5,
                                               float* __restrict__ part) {
    int nt = blockIdx.x;   // 0..15  col tile (64 cols)
    int mi = blockIdx.y;   // 0..5   matrix
    int ks = blockIdx.z;   // 0..KSPLIT-1

    const float* Wsel;
    switch (mi) {
        case 0: Wsel = W0; break;
        case 1: Wsel = W1; break;
        case 2: Wsel = W2; break;
        case 3: Wsel = W3; break;
        case 4: Wsel = W4; break;
        default: Wsel = W5; break;
    }
    int n0 = nt * 64;
    int kbase = ks * KPB;

    __shared__ float xsT[KC][68];   // [k][b]
    __shared__ float wsh[KC][68];   // [k][n]

    int t = threadIdx.x;
    int rg = t >> 4;    // 0..15 -> rows rg*4..rg*4+3 (batch)
    int cg = t & 15;    // 0..15 -> cols cg*4..cg*4+3

    float acc[4][4] = {};

    for (int kc = 0; kc < KPB; kc += KC) {
        int k0 = kbase + kc;
        #pragma unroll
        for (int j = 0; j < 4; j++) {
            int bb = (t >> 4) + j * 16;
            int k4 = (t & 15) * 4;
            float4 xv = *(const float4*)(xn + bb * D_ + k0 + k4);
            xsT[k4 + 0][bb] = xv.x;
            xsT[k4 + 1][bb] = xv.y;
            xsT[k4 + 2][bb] = xv.z;
            xsT[k4 + 3][bb] = xv.w;
            int kk = (t >> 4) + j * 16;
            int n4 = (t & 15) * 4;
            float4 wv = *(const float4*)(Wsel + (size_t)(k0 + kk) * H_ + n0 + n4);
            *(float4*)&wsh[kk][n4] = wv;
        }
        __syncthreads();
        #pragma unroll 8
        for (int kk = 0; kk < KC; kk++) {
            float4 xv = *(const float4*)&xsT[kk][rg * 4];
            float4 wv = *(const float4*)&wsh[kk][cg * 4];
            acc[0][0] += xv.x * wv.x; acc[0][1] += xv.x * wv.y; acc[0][2] += xv.x * wv.z; acc[0][3] += xv.x * wv.w;
            acc[1][0] += xv.y * wv.x; acc[1][1] += xv.y * wv.y; acc[1][2] += xv.y * wv.z; acc[1][3] += xv.y * wv.w;
            acc[2][0] += xv.z * wv.x; acc[2][1] += xv.z * wv.y; acc[2][2] += xv.z * wv.z; acc[2][3] += xv.z * wv.w;
            acc[3][0] += xv.w * wv.x; acc[3][1] += xv.w * wv.y; acc[3][2] += xv.w * wv.z; acc[3][3] += xv.w * wv.w;
        }
        __syncthreads();
    }

    float* pb = part + (size_t)(ks * 6 + mi) * (B_ * H_);
    #pragma unroll
    for (int r = 0; r < 4; r++) {
        int row = rg * 4 + r;
        float4 o = make_float4(acc[r][0], acc[r][1], acc[r][2], acc[r][3]);
        *(float4*)(pb + row * H_ + n0 + cg * 4) = o;
    }
}

// ---------------- K3: gates + n_t, m_t, divisor ----------------
__global__ __launch_bounds__(256) void k3_gates(const float* __restrict__ part,
                                                const float* __restrict__ n_prev,
                                                const float* __restrict__ m_prev,
                                                const float* __restrict__ Bi,
                                                const float* __restrict__ Bf,
                                                const float* __restrict__ Bo,
                                                const float* __restrict__ Bq,
                                                const float* __restrict__ Bk,
                                                const float* __restrict__ Bv,
                                                float* __restrict__ ws,
                                                float* __restrict__ out) {
    int b = blockIdx.x;
    int t = threadIdx.x;
    int v4 = b * (H_ / 4) + t;      // float4 index into [B][H]

    float4 pre[6];
    #pragma unroll
    for (int mi = 0; mi < 6; mi++) {
        float4 s = make_float4(0.f, 0.f, 0.f, 0.f);
        #pragma unroll
        for (int ks = 0; ks < KSPLIT; ks++) {
            float4 p = ((const float4*)part)[(size_t)(ks * 6 + mi) * (B_ * H_ / 4) + v4];
            s.x += p.x; s.y += p.y; s.z += p.z; s.w += p.w;
        }
        pre[mi] = s;
    }

    float4 bi4 = ((const float4*)Bi)[t];
    float4 bf4 = ((const float4*)Bf)[t];
    float4 bo4 = ((const float4*)Bo)[t];
    float4 bq4 = ((const float4*)Bq)[t];
    float4 bk4 = ((const float4*)Bk)[t];
    float4 bv4 = ((const float4*)Bv)[t];
    float4 nn = ((const float4*)(n_prev + b * H_))[t];
    float4 mm = ((const float4*)(m_prev + b * H_))[t];

    const float* pi = (const float*)&pre[0];
    const float* pf = (const float*)&pre[1];
    const float* po = (const float*)&pre[2];
    const float* pq = (const float*)&pre[3];
    const float* pk = (const float*)&pre[4];
    const float* pv = (const float*)&pre[5];
    const float* bi = (const float*)&bi4; const float* bf = (const float*)&bf4;
    const float* bo = (const float*)&bo4; const float* bq = (const float*)&bq4;
    const float* bk = (const float*)&bk4; const float* bv = (const float*)&bv4;
    const float* np_ = (const float*)&nn; const float* mp_ = (const float*)&mm;

    float4 ft4, ip4, ot4, qt4, kt4, vt4, nt4, mt4;
    float* ftp = (float*)&ft4; float* ipp = (float*)&ip4; float* otp = (float*)&ot4;
    float* qtp = (float*)&qt4; float* ktp = (float*)&kt4; float* vtp = (float*)&vt4;
    float* ntp = (float*)&nt4; float* mtp = (float*)&mt4;

    float partial = 0.f;
    #pragma unroll
    for (int c = 0; c < 4; c++) {
        float it_ = clip100(pi[c] + bi[c]);
        float ft_ = clip100(pf[c] + bf[c]);
        float ot_ = clip100(po[c] + bo[c]);
        float qv  = pq[c] + bq[c];
        float kv  = pk[c] * 0.03125f + bk[c];   // /sqrt(1024) before bias
        float vv  = pv[c] + bv[c];

        float i_t = expf(it_);
        float f_t = 1.0f / (1.0f + expf(-ft_));
        float o_t = 1.0f / (1.0f + expf(-ot_));

        float m_t = fmaxf(logf(fmaxf(f_t, 1e-8f)) + mp_[c],
                          logf(fmaxf(i_t, 1e-8f)));
        float ipv = expf(fminf(i_t - m_t, 20.0f));
        float n_t = f_t * np_[c] + ipv * kv;

        ftp[c] = f_t; ipp[c] = ipv; otp[c] = o_t;
        qtp[c] = qv;  ktp[c] = kv;  vtp[c] = vv;
        ntp[c] = n_t; mtp[c] = m_t;
        partial += n_t * qv;
    }

    ((float4*)(ws + OFF_FT))[v4] = ft4;
    ((float4*)(ws + OFF_IP))[v4] = ip4;
    ((float4*)(ws + OFF_OT))[v4] = ot4;
    ((float4*)(ws + OFF_QT))[v4] = qt4;
    ((float4*)(ws + OFF_KT))[v4] = kt4;
    ((float4*)(ws + OFF_VT))[v4] = vt4;
    ((float4*)(out + OUT_N))[v4] = nt4;
    ((float4*)(out + OUT_M))[v4] = mt4;

    __shared__ float red[4];
    #pragma unroll
    for (int off = 32; off; off >>= 1) partial += __shfl_xor(partial, off);
    if ((t & 63) == 0) red[t >> 6] = partial;
    __syncthreads();
    if (t == 0) {
        float tot = red[0] + red[1] + red[2] + red[3];
        ws[OFF_DIV + b] = fmaxf(fabsf(tot), 1.0f);
    }
}

// ---------------- K4: C_t update + fused readout ----------------
__global__ __launch_bounds__(256) void k4_update(const float* __restrict__ C,
                                                 const float* __restrict__ ft,
                                                 const float* __restrict__ ip,
                                                 const float* __restrict__ vt,
                                                 const float* __restrict__ kt,
                                                 const float* __restrict__ qt,
                                                 const float* __restrict__ ot,
                                                 const float* __restrict__ divv,
                                                 float* __restrict__ Ct,
                                                 float* __restrict__ h_out) {
    int b = blockIdx.x >> 8;
    int rg = blockIdx.x & 255;
    int wv = threadIdx.x >> 6;
    int lane = threadIdx.x & 63;
    int i = rg * 4 + wv;

    __shared__ float qS[H_];
    __shared__ float kS[H_];
    ((float4*)qS)[threadIdx.x] = ((const float4*)(qt + b * H_))[threadIdx.x];
    ((float4*)kS)[threadIdx.x] = ((const float4*)(kt + b * H_))[threadIdx.x];
    __syncthreads();

    size_t rowoff = ((size_t)b * H_ + i) * H_;
    const float4* Crow = (const float4*)(C + rowoff);
    float4* Orow = (float4*)(Ct + rowoff);

    int gi = b * H_ + i;
    float f = ft[gi];
    float w = ip[gi] * vt[gi];

    float dot = 0.f;
    #pragma unroll
    for (int c = 0; c < 4; c++) {
        int q4 = c * 64 + lane;     // float4 index within row
        float4 cv = Crow[q4];
        float4 kk = ((const float4*)kS)[q4];
        float4 qq = ((const float4*)qS)[q4];
        float4 o;
        o.x = f * cv.x + w * kk.x;
        o.y = f * cv.y + w * kk.y;
        o.z = f * cv.z + w * kk.z;
        o.w = f * cv.w + w * kk.w;
        dot += o.x * qq.x + o.y * qq.y + o.z * qq.z + o.w * qq.w;
        Orow[q4] = o;
    }

    #pragma unroll
    for (int off = 32; off; off >>= 1) dot += __shfl_xor(dot, off);
    if (lane == 0) {
        h_out[gi] = ot[gi] * dot / divv[b];
    }
}

extern "C" void kernel_launch(void* const* d_in, const int* in_sizes, int n_in,
                              void* d_out, int out_size, void* d_ws, size_t ws_size,
                              hipStream_t stream) {
    const float* x      = (const float*)d_in[0];
    const float* C      = (const float*)d_in[1];
    const float* n_prev = (const float*)d_in[2];
    const float* m_prev = (const float*)d_in[3];
    const float* Wi     = (const float*)d_in[4];
    const float* Wf     = (const float*)d_in[5];
    const float* Wo     = (const float*)d_in[6];
    const float* Wq     = (const float*)d_in[7];
    const float* Wk     = (const float*)d_in[8];
    const float* Wv     = (const float*)d_in[9];
    const float* Bi     = (const float*)d_in[10];
    const float* Bf     = (const float*)d_in[11];
    const float* Bo     = (const float*)d_in[12];
    const float* Bq     = (const float*)d_in[13];
    const float* Bk     = (const float*)d_in[14];
    const float* Bv     = (const float*)d_in[15];
    const float* gamma  = (const float*)d_in[16];
    const float* beta   = (const float*)d_in[17];

    float* out = (float*)d_out;
    float* ws  = (float*)d_ws;

    float* xn   = ws + OFF_XN;
    float* part = ws + OFF_PART;

    k1_ln<<<B_, 256, 0, stream>>>(x, gamma, beta, xn);

    dim3 g2(16, 6, KSPLIT);
    k2_gemm<<<g2, 256, 0, stream>>>(xn, Wi, Wf, Wo, Wq, Wk, Wv, part);

    k3_gates<<<B_, 256, 0, stream>>>(part, n_prev, m_prev, Bi, Bf, Bo, Bq, Bk, Bv, ws, out);

    k4_update<<<B_ * 256, 256, 0, stream>>>(C,
                                            ws + OFF_FT, ws + OFF_IP, ws + OFF_VT,
                                            ws + OFF_KT, ws + OFF_QT, ws + OFF_OT,
                                            ws + OFF_DIV,
                                            out + OUT_C, out + OUT_H);
}

// Round 6
// 494.798 us; speedup vs baseline: 1.0057x; 1.0057x over previous
//
#include <hip/hip_runtime.h>
#include <math.h>

#define B_ 64
#define D_ 1024
#define H_ 1024
#define KSPLIT 4
#define KPB (D_/KSPLIT)   // 256 K-depth per block in K2
#define KC 64             // K chunk staged in LDS

typedef float f4 __attribute__((ext_vector_type(4)));

// ---- workspace layout (floats) ----
#define OFF_XN    0
#define OFF_PART  (OFF_XN + B_*D_)                 // 6 matrices x KSPLIT partials
#define OFF_FT    (OFF_PART + KSPLIT*6*B_*H_)
#define OFF_IP    (OFF_FT + B_*H_)
#define OFF_OT    (OFF_IP + B_*H_)
#define OFF_QT    (OFF_OT + B_*H_)
#define OFF_KT    (OFF_QT + B_*H_)
#define OFF_VT    (OFF_KT + B_*H_)
#define OFF_DIV   (OFF_VT + B_*H_)

// ---- output layout (floats) ----
#define OUT_H 0
#define OUT_C (B_*H_)
#define OUT_N (OUT_C + B_*H_*H_)
#define OUT_M (OUT_N + B_*H_)

__device__ __forceinline__ float clip100(float v) {
    return fminf(fmaxf(v, -100.0f), 100.0f);
}

// ---------------- K1: LayerNorm ----------------
__global__ __launch_bounds__(256) void k1_ln(const float* __restrict__ x,
                                             const float* __restrict__ gamma,
                                             const float* __restrict__ beta,
                                             float* __restrict__ xn) {
    int b = blockIdx.x;
    int t = threadIdx.x;
    const float4* x4 = (const float4*)(x + b * D_);
    float4 v = x4[t];
    __shared__ float red[4];

    float s = v.x + v.y + v.z + v.w;
    #pragma unroll
    for (int off = 32; off; off >>= 1) s += __shfl_xor(s, off);
    if ((t & 63) == 0) red[t >> 6] = s;
    __syncthreads();
    float mean = (red[0] + red[1] + red[2] + red[3]) * (1.0f / D_);

    float dx = v.x - mean, dy = v.y - mean, dz = v.z - mean, dw = v.w - mean;
    float s2 = dx*dx + dy*dy + dz*dz + dw*dw;
    __syncthreads();
    #pragma unroll
    for (int off = 32; off; off >>= 1) s2 += __shfl_xor(s2, off);
    if ((t & 63) == 0) red[t >> 6] = s2;
    __syncthreads();
    float var = (red[0] + red[1] + red[2] + red[3]) * (1.0f / D_);
    float rstd = 1.0f / sqrtf(var + 1e-5f);

    float4 g = ((const float4*)gamma)[t];
    float4 be = ((const float4*)beta)[t];
    float4 o;
    o.x = dx * rstd * g.x + be.x;
    o.y = dy * rstd * g.y + be.y;
    o.z = dz * rstd * g.z + be.z;
    o.w = dw * rstd * g.w + be.w;
    ((float4*)(xn + b * D_))[t] = o;
}

// ---------------- K2: 6x GEMM (xn @ W), K-split partials ----------------
__global__ __launch_bounds__(256) void k2_gemm(const float* __restrict__ xn,
                                               const float* __restrict__ W0,
                                               const float* __restrict__ W1,
                                               const float* __restrict__ W2,
                                               const float* __restrict__ W3,
                                               const float* __restrict__ W4,
                                               const float* __restrict__ W5,
                                               float* __restrict__ part) {
    int nt = blockIdx.x;   // 0..15  col tile (64 cols)
    int mi = blockIdx.y;   // 0..5   matrix
    int ks = blockIdx.z;   // 0..KSPLIT-1

    const float* Wsel;
    switch (mi) {
        case 0: Wsel = W0; break;
        case 1: Wsel = W1; break;
        case 2: Wsel = W2; break;
        case 3: Wsel = W3; break;
        case 4: Wsel = W4; break;
        default: Wsel = W5; break;
    }
    int n0 = nt * 64;
    int kbase = ks * KPB;

    __shared__ float xsT[KC][68];   // [k][b]
    __shared__ float wsh[KC][68];   // [k][n]

    int t = threadIdx.x;
    int rg = t >> 4;    // 0..15 -> rows rg*4..rg*4+3 (batch)
    int cg = t & 15;    // 0..15 -> cols cg*4..cg*4+3

    float acc[4][4] = {};

    for (int kc = 0; kc < KPB; kc += KC) {
        int k0 = kbase + kc;
        #pragma unroll
        for (int j = 0; j < 4; j++) {
            int bb = (t >> 4) + j * 16;
            int k4 = (t & 15) * 4;
            float4 xv = *(const float4*)(xn + bb * D_ + k0 + k4);
            xsT[k4 + 0][bb] = xv.x;
            xsT[k4 + 1][bb] = xv.y;
            xsT[k4 + 2][bb] = xv.z;
            xsT[k4 + 3][bb] = xv.w;
            int kk = (t >> 4) + j * 16;
            int n4 = (t & 15) * 4;
            float4 wv = *(const float4*)(Wsel + (size_t)(k0 + kk) * H_ + n0 + n4);
            *(float4*)&wsh[kk][n4] = wv;
        }
        __syncthreads();
        #pragma unroll 8
        for (int kk = 0; kk < KC; kk++) {
            float4 xv = *(const float4*)&xsT[kk][rg * 4];
            float4 wv = *(const float4*)&wsh[kk][cg * 4];
            acc[0][0] += xv.x * wv.x; acc[0][1] += xv.x * wv.y; acc[0][2] += xv.x * wv.z; acc[0][3] += xv.x * wv.w;
            acc[1][0] += xv.y * wv.x; acc[1][1] += xv.y * wv.y; acc[1][2] += xv.y * wv.z; acc[1][3] += xv.y * wv.w;
            acc[2][0] += xv.z * wv.x; acc[2][1] += xv.z * wv.y; acc[2][2] += xv.z * wv.z; acc[2][3] += xv.z * wv.w;
            acc[3][0] += xv.w * wv.x; acc[3][1] += xv.w * wv.y; acc[3][2] += xv.w * wv.z; acc[3][3] += xv.w * wv.w;
        }
        __syncthreads();
    }

    float* pb = part + (size_t)(ks * 6 + mi) * (B_ * H_);
    #pragma unroll
    for (int r = 0; r < 4; r++) {
        int row = rg * 4 + r;
        float4 o = make_float4(acc[r][0], acc[r][1], acc[r][2], acc[r][3]);
        *(float4*)(pb + row * H_ + n0 + cg * 4) = o;
    }
}

// ---------------- K3: gates + n_t, m_t, divisor ----------------
__global__ __launch_bounds__(256) void k3_gates(const float* __restrict__ part,
                                                const float* __restrict__ n_prev,
                                                const float* __restrict__ m_prev,
                                                const float* __restrict__ Bi,
                                                const float* __restrict__ Bf,
                                                const float* __restrict__ Bo,
                                                const float* __restrict__ Bq,
                                                const float* __restrict__ Bk,
                                                const float* __restrict__ Bv,
                                                float* __restrict__ ws,
                                                float* __restrict__ out) {
    int b = blockIdx.x;
    int t = threadIdx.x;
    int v4 = b * (H_ / 4) + t;      // float4 index into [B][H]

    float4 pre[6];
    #pragma unroll
    for (int mi = 0; mi < 6; mi++) {
        float4 s = make_float4(0.f, 0.f, 0.f, 0.f);
        #pragma unroll
        for (int ks = 0; ks < KSPLIT; ks++) {
            float4 p = ((const float4*)part)[(size_t)(ks * 6 + mi) * (B_ * H_ / 4) + v4];
            s.x += p.x; s.y += p.y; s.z += p.z; s.w += p.w;
        }
        pre[mi] = s;
    }

    float4 bi4 = ((const float4*)Bi)[t];
    float4 bf4 = ((const float4*)Bf)[t];
    float4 bo4 = ((const float4*)Bo)[t];
    float4 bq4 = ((const float4*)Bq)[t];
    float4 bk4 = ((const float4*)Bk)[t];
    float4 bv4 = ((const float4*)Bv)[t];
    float4 nn = ((const float4*)(n_prev + b * H_))[t];
    float4 mm = ((const float4*)(m_prev + b * H_))[t];

    const float* pi = (const float*)&pre[0];
    const float* pf = (const float*)&pre[1];
    const float* po = (const float*)&pre[2];
    const float* pq = (const float*)&pre[3];
    const float* pk = (const float*)&pre[4];
    const float* pv = (const float*)&pre[5];
    const float* bi = (const float*)&bi4; const float* bf = (const float*)&bf4;
    const float* bo = (const float*)&bo4; const float* bq = (const float*)&bq4;
    const float* bk = (const float*)&bk4; const float* bv = (const float*)&bv4;
    const float* np_ = (const float*)&nn; const float* mp_ = (const float*)&mm;

    float4 ft4, ip4, ot4, qt4, kt4, vt4, nt4, mt4;
    float* ftp = (float*)&ft4; float* ipp = (float*)&ip4; float* otp = (float*)&ot4;
    float* qtp = (float*)&qt4; float* ktp = (float*)&kt4; float* vtp = (float*)&vt4;
    float* ntp = (float*)&nt4; float* mtp = (float*)&mt4;

    float partial = 0.f;
    #pragma unroll
    for (int c = 0; c < 4; c++) {
        float it_ = clip100(pi[c] + bi[c]);
        float ft_ = clip100(pf[c] + bf[c]);
        float ot_ = clip100(po[c] + bo[c]);
        float qv  = pq[c] + bq[c];
        float kv  = pk[c] * 0.03125f + bk[c];   // /sqrt(1024) before bias
        float vv  = pv[c] + bv[c];

        float i_t = expf(it_);
        float f_t = 1.0f / (1.0f + expf(-ft_));
        float o_t = 1.0f / (1.0f + expf(-ot_));

        float m_t = fmaxf(logf(fmaxf(f_t, 1e-8f)) + mp_[c],
                          logf(fmaxf(i_t, 1e-8f)));
        float ipv = expf(fminf(i_t - m_t, 20.0f));
        float n_t = f_t * np_[c] + ipv * kv;

        ftp[c] = f_t; ipp[c] = ipv; otp[c] = o_t;
        qtp[c] = qv;  ktp[c] = kv;  vtp[c] = vv;
        ntp[c] = n_t; mtp[c] = m_t;
        partial += n_t * qv;
    }

    ((float4*)(ws + OFF_FT))[v4] = ft4;
    ((float4*)(ws + OFF_IP))[v4] = ip4;
    ((float4*)(ws + OFF_OT))[v4] = ot4;
    ((float4*)(ws + OFF_QT))[v4] = qt4;
    ((float4*)(ws + OFF_KT))[v4] = kt4;
    ((float4*)(ws + OFF_VT))[v4] = vt4;
    ((float4*)(out + OUT_N))[v4] = nt4;
    ((float4*)(out + OUT_M))[v4] = mt4;

    __shared__ float red[4];
    #pragma unroll
    for (int off = 32; off; off >>= 1) partial += __shfl_xor(partial, off);
    if ((t & 63) == 0) red[t >> 6] = partial;
    __syncthreads();
    if (t == 0) {
        float tot = red[0] + red[1] + red[2] + red[3];
        ws[OFF_DIV + b] = fmaxf(fabsf(tot), 1.0f);
    }
}

// ---------------- K4: C_t update + fused readout (v2: no LDS, no barriers,
// q/k in registers, 4 rows/wave, nontemporal C stream) ----------------
__global__ __launch_bounds__(256) void k4_update(const float* __restrict__ C,
                                                 const float* __restrict__ ft,
                                                 const float* __restrict__ ip,
                                                 const float* __restrict__ vt,
                                                 const float* __restrict__ kt,
                                                 const float* __restrict__ qt,
                                                 const float* __restrict__ ot,
                                                 const float* __restrict__ divv,
                                                 float* __restrict__ Ct,
                                                 float* __restrict__ h_out) {
    int b   = blockIdx.x >> 6;          // 0..63 batch
    int rg0 = (blockIdx.x & 63) << 4;   // 16 rows per block
    int wv  = threadIdx.x >> 6;         // wave 0..3
    int lane = threadIdx.x & 63;

    // per-lane q/k fragments: lane only ever touches float4 index c*64+lane
    const f4* qv4 = (const f4*)(qt + b * H_);
    const f4* kv4 = (const f4*)(kt + b * H_);
    f4 qf[4], kf[4];
    #pragma unroll
    for (int c = 0; c < 4; c++) {
        qf[c] = qv4[c * 64 + lane];
        kf[c] = kv4[c * 64 + lane];
    }
    float divb = divv[b];

    #pragma unroll
    for (int rr = 0; rr < 4; rr++) {
        int i = rg0 + wv * 4 + rr;      // wave wv owns rows wv*4 .. wv*4+3
        int gi = b * H_ + i;
        float f = ft[gi];
        float w = ip[gi] * vt[gi];
        size_t rowoff = ((size_t)b * H_ + i) * H_;
        const f4* Crow = (const f4*)(C + rowoff);
        f4* Orow = (f4*)(Ct + rowoff);

        float dot = 0.f;
        #pragma unroll
        for (int c = 0; c < 4; c++) {
            f4 cv = __builtin_nontemporal_load(Crow + c * 64 + lane);
            f4 o = f * cv + w * kf[c];
            f4 qq = qf[c];
            dot += o.x * qq.x + o.y * qq.y + o.z * qq.z + o.w * qq.w;
            __builtin_nontemporal_store(o, Orow + c * 64 + lane);
        }

        #pragma unroll
        for (int off = 32; off; off >>= 1) dot += __shfl_xor(dot, off);
        if (lane == 0) {
            h_out[gi] = ot[gi] * dot / divb;
        }
    }
}

extern "C" void kernel_launch(void* const* d_in, const int* in_sizes, int n_in,
                              void* d_out, int out_size, void* d_ws, size_t ws_size,
                              hipStream_t stream) {
    const float* x      = (const float*)d_in[0];
    const float* C      = (const float*)d_in[1];
    const float* n_prev = (const float*)d_in[2];
    const float* m_prev = (const float*)d_in[3];
    const float* Wi     = (const float*)d_in[4];
    const float* Wf     = (const float*)d_in[5];
    const float* Wo     = (const float*)d_in[6];
    const float* Wq     = (const float*)d_in[7];
    const float* Wk     = (const float*)d_in[8];
    const float* Wv     = (const float*)d_in[9];
    const float* Bi     = (const float*)d_in[10];
    const float* Bf     = (const float*)d_in[11];
    const float* Bo     = (const float*)d_in[12];
    const float* Bq     = (const float*)d_in[13];
    const float* Bk     = (const float*)d_in[14];
    const float* Bv     = (const float*)d_in[15];
    const float* gamma  = (const float*)d_in[16];
    const float* beta   = (const float*)d_in[17];

    float* out = (float*)d_out;
    float* ws  = (float*)d_ws;

    float* xn   = ws + OFF_XN;
    float* part = ws + OFF_PART;

    k1_ln<<<B_, 256, 0, stream>>>(x, gamma, beta, xn);

    dim3 g2(16, 6, KSPLIT);
    k2_gemm<<<g2, 256, 0, stream>>>(xn, Wi, Wf, Wo, Wq, Wk, Wv, part);

    k3_gates<<<B_, 256, 0, stream>>>(part, n_prev, m_prev, Bi, Bf, Bo, Bq, Bk, Bv, ws, out);

    k4_update<<<B_ * 64, 256, 0, stream>>>(C,
                                           ws + OFF_FT, ws + OFF_IP, ws + OFF_VT,
                                           ws + OFF_KT, ws + OFF_QT, ws + OFF_OT,
                                           ws + OFF_DIV,
                                           out + OUT_C, out + OUT_H);
}